// Round 1
// baseline (99.673 us; speedup 1.0000x reference)
//
#include <hip/hip_runtime.h>

// Empirical-CDF calibration: out = lerp over sorted table ri (R=4096), ro = j/(R-1).
// Strategy: uniform-grid LUT (M=8192 cells over [ri[0], ri[R-1]]) -> start index,
// then a provably-bounded (<=2) branchless advance. ri + LUT staged in LDS.

#define LUT_M 8192
#define RI_MAX 4096

__global__ __launch_bounds__(256) void build_lut_kernel(
    const float* __restrict__ ri, int R, unsigned short* __restrict__ lut)
{
    __shared__ float s_ri[RI_MAX];
    int Rc = min(R, RI_MAX);
    for (int i = threadIdx.x; i < Rc; i += blockDim.x)
        s_ri[i] = ri[i];
    __syncthreads();

    int k = blockIdx.x * blockDim.x + threadIdx.x;
    if (k >= LUT_M) return;
    float lo = s_ri[0];
    float hi = s_ri[Rc - 1];
    float cell_left = lo + (hi - lo) * ((float)k * (1.0f / (float)LUT_M));
    // upper_bound: first j with ri[j] > cell_left
    int a = 0, b = Rc;
    while (a < b) {
        int mid = (a + b) >> 1;
        if (s_ri[mid] > cell_left) b = mid; else a = mid + 1;
    }
    a = min(max(a, 1), Rc - 1);
    lut[k] = (unsigned short)a;
}

__device__ __forceinline__ float calib_one(
    float xv, float lo, float hi, float y_lo, float y_hi,
    float scale, float inv_rm1, int Rm1,
    const float* __restrict__ s_ri, const unsigned short* __restrict__ s_lut)
{
    int k = (int)((xv - lo) * scale);
    k = min(max(k, 0), LUT_M - 1);
    int j = (int)s_lut[k];
    // adjacent dwords -> ds_read2_b32
    float x0 = s_ri[j - 1];
    float x1 = s_ri[j];
#pragma unroll
    for (int s = 0; s < 2; ++s) {   // <=2 table points per cell (cell < 2*min spacing)
        int jn = min(j + 1, Rm1);
        float xn = s_ri[jn];
        bool adv = (x1 <= xv);
        x0 = adv ? x1 : x0;
        j  = adv ? jn : j;
        x1 = adv ? xn : x1;
    }
    float y0 = (float)(j - 1) * inv_rm1;
    float res = fmaf(inv_rm1 * (xv - x0), __builtin_amdgcn_rcpf(x1 - x0), y0);
    res = (xv <= lo) ? y_lo : res;
    res = (xv >= hi) ? y_hi : res;
    return res;
}

__global__ __launch_bounds__(256, 5) void calib_main_kernel(
    const float* __restrict__ x, int n, int n4,
    const float* __restrict__ ri, const float* __restrict__ ro, int R,
    const unsigned short* __restrict__ lut,
    float* __restrict__ out)
{
    __shared__ float s_ri[RI_MAX];
    __shared__ unsigned short s_lut[LUT_M];

    int Rc = min(R, RI_MAX);
    // stage ri (16 KB) and LUT (16 KB) with 16B vector loads
    for (int i = threadIdx.x; i < (Rc >> 2); i += blockDim.x)
        ((float4*)s_ri)[i] = ((const float4*)ri)[i];
    for (int i = threadIdx.x; i < (LUT_M >> 3); i += blockDim.x)
        ((uint4*)s_lut)[i] = ((const uint4*)lut)[i];
    __syncthreads();

    const float lo = s_ri[0];
    const float hi = s_ri[Rc - 1];
    const float y_lo = ro[0];
    const float y_hi = ro[Rc - 1];
    const float scale = (float)LUT_M / (hi - lo);
    const float inv_rm1 = 1.0f / (float)(Rc - 1);
    const int Rm1 = Rc - 1;

    const float4* __restrict__ x4 = (const float4*)x;
    float4* __restrict__ out4 = (float4*)out;

    const int tid = blockIdx.x * blockDim.x + threadIdx.x;
    const int stride = gridDim.x * blockDim.x;
    for (int i = tid; i < n4; i += stride) {
        float4 v = x4[i];
        float4 r;
        r.x = calib_one(v.x, lo, hi, y_lo, y_hi, scale, inv_rm1, Rm1, s_ri, s_lut);
        r.y = calib_one(v.y, lo, hi, y_lo, y_hi, scale, inv_rm1, Rm1, s_ri, s_lut);
        r.z = calib_one(v.z, lo, hi, y_lo, y_hi, scale, inv_rm1, Rm1, s_ri, s_lut);
        r.w = calib_one(v.w, lo, hi, y_lo, y_hi, scale, inv_rm1, Rm1, s_ri, s_lut);
        out4[i] = r;
    }

    // scalar tail (BATCH is a multiple of 4, but stay correct generally)
    int base = n4 << 2;
    int rem = n - base;
    if (blockIdx.x == 0 && (int)threadIdx.x < rem) {
        int i = base + (int)threadIdx.x;
        out[i] = calib_one(x[i], lo, hi, y_lo, y_hi, scale, inv_rm1, Rm1, s_ri, s_lut);
    }
}

extern "C" void kernel_launch(void* const* d_in, const int* in_sizes, int n_in,
                              void* d_out, int out_size, void* d_ws, size_t ws_size,
                              hipStream_t stream)
{
    const float* x  = (const float*)d_in[0];
    const float* ri = (const float*)d_in[1];
    const float* ro = (const float*)d_in[2];
    float* out = (float*)d_out;
    const int R = in_sizes[1];
    unsigned short* lut = (unsigned short*)d_ws;

    build_lut_kernel<<<LUT_M / 256, 256, 0, stream>>>(ri, R, lut);

    const int n = out_size;
    const int n4 = n >> 2;
    // 5 blocks/CU (32 KB LDS each) x 256 CUs
    const int grid = 1280;
    calib_main_kernel<<<grid, 256, 0, stream>>>(x, n, n4, ri, ro, R, lut, out);
}

// Round 2
// 94.888 us; speedup vs baseline: 1.0504x; 1.0504x over previous
//
#include <hip/hip_runtime.h>

// Empirical-CDF calibration, dense-LUT formulation.
//
// y(x) is monotone piecewise-linear with max slope ~phi(0)/1 ~ 0.4 and output
// tolerance 2e-2 absolute. So instead of searching the 4096-entry table per
// element, kernel 1 evaluates the EXACT reference calibration at M+1 uniform
// x-grid edges (secant error per cell <= 0.4*(range/M) ~ 3.6e-4 << 2e-2), and
// kernel 2 does one fma + one adjacent-pair LDS read per element.

#define M_CELLS 8192
#define RI_MAX  4096

__global__ __launch_bounds__(256) void build_edges_kernel(
    const float* __restrict__ ri, const float* __restrict__ ro, int R,
    float* __restrict__ edge)
{
    __shared__ float s_ri[RI_MAX];
    int Rc = min(R, RI_MAX);
    for (int i = threadIdx.x; i < Rc; i += blockDim.x)
        s_ri[i] = ri[i];
    __syncthreads();

    int k = blockIdx.x * blockDim.x + threadIdx.x;
    if (k > M_CELLS) return;

    float lo = s_ri[0];
    float hi = s_ri[Rc - 1];
    float xk = lo + (hi - lo) * ((float)k * (1.0f / (float)M_CELLS));

    // upper_bound: first j with ri[j] > xk  (searchsorted side='right')
    int a = 0, b = Rc;
    while (a < b) {
        int mid = (a + b) >> 1;
        if (s_ri[mid] > xk) b = mid; else a = mid + 1;
    }
    int idx = min(max(a, 1), Rc - 1);

    float x0 = s_ri[idx - 1];
    float x1 = s_ri[idx];
    float y0 = ro[idx - 1];
    float y1 = ro[idx];
    float interp = y0 + (y1 - y0) / (x1 - x0) * (xk - x0);
    // exact reference edge semantics
    interp = (xk <= lo) ? ro[0]      : interp;
    interp = (xk >= hi) ? ro[Rc - 1] : interp;
    edge[k] = interp;
}

__global__ __launch_bounds__(256, 4) void calib_main_kernel(
    const float* __restrict__ x, int n, int n4,
    const float* __restrict__ ri, int R,
    const float* __restrict__ edge,
    float* __restrict__ out)
{
    __shared__ float s_edge[M_CELLS + 1];

    // stage 8193 floats with 16B vector loads (+1 scalar)
    for (int i = threadIdx.x; i < (M_CELLS >> 2); i += blockDim.x)
        ((float4*)s_edge)[i] = ((const float4*)edge)[i];
    if (threadIdx.x == 0)
        s_edge[M_CELLS] = edge[M_CELLS];
    __syncthreads();

    const float lo = ri[0];
    const float hi = ri[R - 1];
    const float y_lo = s_edge[0];
    const float y_hi = s_edge[M_CELLS];
    const float scale = (float)M_CELLS / (hi - lo);

    const float4* __restrict__ x4 = (const float4*)x;
    float4* __restrict__ out4 = (float4*)out;

    const int tid = blockIdx.x * blockDim.x + threadIdx.x;
    const int stride = gridDim.x * blockDim.x;

    for (int i = tid; i < n4; i += stride) {
        float4 v = x4[i];
        float4 r;
        float* vp = &v.x;
        float* rp = &r.x;
#pragma unroll
        for (int c = 0; c < 4; ++c) {
            float xv = vp[c];
            float t = (xv - lo) * scale;
            int k = (int)t;
            k = min(max(k, 0), M_CELLS - 1);
            float frac = t - (float)k;
            float e0 = s_edge[k];       // adjacent pair -> ds_read2_b32
            float e1 = s_edge[k + 1];
            float res = fmaf(frac, e1 - e0, e0);
            res = (xv <= lo) ? y_lo : res;
            res = (xv >= hi) ? y_hi : res;
            rp[c] = res;
        }
        out4[i] = r;
    }

    // scalar tail (n is a multiple of 4 here, but stay correct generally)
    int base = n4 << 2;
    int rem = n - base;
    if (blockIdx.x == 0 && (int)threadIdx.x < rem) {
        int i = base + (int)threadIdx.x;
        float xv = x[i];
        float t = (xv - lo) * scale;
        int k = (int)t;
        k = min(max(k, 0), M_CELLS - 1);
        float frac = t - (float)k;
        float res = fmaf(frac, s_edge[k + 1] - s_edge[k], s_edge[k]);
        res = (xv <= lo) ? y_lo : res;
        res = (xv >= hi) ? y_hi : res;
        out[i] = res;
    }
}

extern "C" void kernel_launch(void* const* d_in, const int* in_sizes, int n_in,
                              void* d_out, int out_size, void* d_ws, size_t ws_size,
                              hipStream_t stream)
{
    const float* x  = (const float*)d_in[0];
    const float* ri = (const float*)d_in[1];
    const float* ro = (const float*)d_in[2];
    float* out = (float*)d_out;
    const int R = in_sizes[1];
    float* edge = (float*)d_ws;   // M_CELLS+1 floats

    build_edges_kernel<<<(M_CELLS + 256) / 256, 256, 0, stream>>>(ri, ro, R, edge);

    const int n = out_size;
    const int n4 = n >> 2;
    // 4 blocks/CU (32.8 KB LDS each) x 256 CUs
    const int grid = 1024;
    calib_main_kernel<<<grid, 256, 0, stream>>>(x, n, n4, ri, R, edge, out);
}

// Round 3
// 92.009 us; speedup vs baseline: 1.0833x; 1.0313x over previous
//
#include <hip/hip_runtime.h>

// Empirical-CDF calibration, dense-LUT formulation, occupancy-tuned.
//
// Kernel 1 evaluates the EXACT reference calibration at M+1 uniform x-grid
// edges (secant error <= 0.4*(range/M)/2 ~ 7e-4 << 2e-2 threshold).
// Kernel 2: per element, one fma + one adjacent-pair LDS read + one fma.
// M=2048 -> 8.2 KB LDS -> 8 blocks/CU (32 waves/CU) for full HBM latency hiding.

#define M_CELLS 2048
#define RI_MAX  4096

__global__ __launch_bounds__(256) void build_edges_kernel(
    const float* __restrict__ ri, const float* __restrict__ ro, int R,
    float* __restrict__ edge)
{
    __shared__ float s_ri[RI_MAX];
    int Rc = min(R, RI_MAX);
    for (int i = threadIdx.x; i < Rc; i += blockDim.x)
        s_ri[i] = ri[i];
    __syncthreads();

    int k = blockIdx.x * blockDim.x + threadIdx.x;
    if (k > M_CELLS) return;

    float lo = s_ri[0];
    float hi = s_ri[Rc - 1];
    float xk = lo + (hi - lo) * ((float)k * (1.0f / (float)M_CELLS));

    // upper_bound: first j with ri[j] > xk  (searchsorted side='right')
    int a = 0, b = Rc;
    while (a < b) {
        int mid = (a + b) >> 1;
        if (s_ri[mid] > xk) b = mid; else a = mid + 1;
    }
    int idx = min(max(a, 1), Rc - 1);

    float x0 = s_ri[idx - 1];
    float x1 = s_ri[idx];
    float y0 = ro[idx - 1];
    float y1 = ro[idx];
    float interp = y0 + (y1 - y0) / (x1 - x0) * (xk - x0);
    // exact reference edge semantics
    interp = (xk <= lo) ? ro[0]      : interp;
    interp = (xk >= hi) ? ro[Rc - 1] : interp;
    edge[k] = interp;
}

__global__ __launch_bounds__(256, 8) void calib_main_kernel(
    const float* __restrict__ x, int n, int n4,
    const float* __restrict__ ri, int R,
    const float* __restrict__ edge,
    float* __restrict__ out)
{
    __shared__ float s_edge[M_CELLS + 1];

    // stage 2049 floats with 16B vector loads (+1 scalar)
    for (int i = threadIdx.x; i < (M_CELLS >> 2); i += blockDim.x)
        ((float4*)s_edge)[i] = ((const float4*)edge)[i];
    if (threadIdx.x == 0)
        s_edge[M_CELLS] = edge[M_CELLS];
    __syncthreads();

    const float lo = ri[0];
    const float hi = ri[R - 1];
    const float y_lo = s_edge[0];
    const float y_hi = s_edge[M_CELLS];
    const float scale = (float)M_CELLS / (hi - lo);

    const float4* __restrict__ x4 = (const float4*)x;
    float4* __restrict__ out4 = (float4*)out;

    const int tid = blockIdx.x * blockDim.x + threadIdx.x;
    const int stride = gridDim.x * blockDim.x;

    for (int i = tid; i < n4; i += stride) {
        float4 v = x4[i];
        float4 r;
        float* vp = &v.x;
        float* rp = &r.x;
#pragma unroll
        for (int c = 0; c < 4; ++c) {
            float xv = vp[c];
            float t = (xv - lo) * scale;
            int k = (int)t;
            k = min(max(k, 0), M_CELLS - 1);
            float frac = t - (float)k;
            float e0 = s_edge[k];       // adjacent pair -> ds_read2_b32
            float e1 = s_edge[k + 1];
            float res = fmaf(frac, e1 - e0, e0);
            res = (xv <= lo) ? y_lo : res;
            res = (xv >= hi) ? y_hi : res;
            rp[c] = res;
        }
        out4[i] = r;
    }

    // scalar tail (n is a multiple of 4 here, but stay correct generally)
    int base = n4 << 2;
    int rem = n - base;
    if (blockIdx.x == 0 && (int)threadIdx.x < rem) {
        int i = base + (int)threadIdx.x;
        float xv = x[i];
        float t = (xv - lo) * scale;
        int k = (int)t;
        k = min(max(k, 0), M_CELLS - 1);
        float frac = t - (float)k;
        float res = fmaf(frac, s_edge[k + 1] - s_edge[k], s_edge[k]);
        res = (xv <= lo) ? y_lo : res;
        res = (xv >= hi) ? y_hi : res;
        out[i] = res;
    }
}

extern "C" void kernel_launch(void* const* d_in, const int* in_sizes, int n_in,
                              void* d_out, int out_size, void* d_ws, size_t ws_size,
                              hipStream_t stream)
{
    const float* x  = (const float*)d_in[0];
    const float* ri = (const float*)d_in[1];
    const float* ro = (const float*)d_in[2];
    float* out = (float*)d_out;
    const int R = in_sizes[1];
    float* edge = (float*)d_ws;   // M_CELLS+1 floats

    build_edges_kernel<<<(M_CELLS + 1 + 255) / 256, 256, 0, stream>>>(ri, ro, R, edge);

    const int n = out_size;
    const int n4 = n >> 2;
    // 8 blocks/CU (8.2 KB LDS each, 32 waves/CU) x 256 CUs
    const int grid = 2048;
    calib_main_kernel<<<grid, 256, 0, stream>>>(x, n, n4, ri, R, edge, out);
}